// Round 1
// baseline (1772.961 us; speedup 1.0000x reference)
//
#include <hip/hip_runtime.h>
#include <stdint.h>

#define N_T 32768
#define N_Q 4096
#define E_T 1048576
#define E_Q 131072
#define H   128
#define NL  3

// ---------------- utility kernels ----------------
__global__ void zero_i32_k(int* p, int n){
  int i = blockIdx.x*blockDim.x + threadIdx.x;
  if(i<n) p[i]=0;
}
__global__ void zero_f32_k(float* p, int n){
  int i = blockIdx.x*blockDim.x + threadIdx.x;
  if(i<n) p[i]=0.f;
}

// classify mask dtype: flag bit0 -> uint8 bools, bit1 -> float32, 0 -> int32
__global__ void detect_mask_k(const unsigned* m, int* flag){
  int t = threadIdx.x;
  int f = 0;
  for(int j=t;j<4096;j+=256){
    unsigned v = m[j];
    if(v > 1u) f |= (v & 0xFEFEFEFEu) ? 2 : 1;
  }
  if(f) atomicOr(flag, f);
}

// ---------------- CSR build ----------------
__global__ void count_k(const int* __restrict__ dst, int E, int* cnt){
  int i = blockIdx.x*blockDim.x + threadIdx.x;
  if(i<E) atomicAdd(&cnt[dst[i]], 1);
}

__global__ void scan_k(const int* __restrict__ cnt, int n, int* rp, int* pos){
  __shared__ int part[1024];
  int t = threadIdx.x;
  int chunk = (n + 1023) >> 10;
  int lo = t*chunk, hi = lo+chunk; if(hi>n) hi=n;
  int s = 0;
  for(int i=lo;i<hi;i++) s += cnt[i];
  part[t] = s;
  __syncthreads();
  for(int off=1; off<1024; off<<=1){
    int v = (t >= off) ? part[t-off] : 0;
    __syncthreads();
    part[t] += v;
    __syncthreads();
  }
  int run = (t==0) ? 0 : part[t-1];
  for(int i=lo;i<hi;i++){ rp[i]=run; pos[i]=run; run += cnt[i]; }
  if(t==0) rp[n] = part[1023];
}

__global__ void fill_k(const int* __restrict__ src, const int* __restrict__ dst,
                       int E, int* pos, int* csr){
  int i = blockIdx.x*blockDim.x + threadIdx.x;
  if(i<E){
    int p = atomicAdd(&pos[dst[i]], 1);
    csr[p] = src[i];
  }
}

// ---------------- embedding gather ----------------
__global__ void embed_k(const int* __restrict__ idx, const float* __restrict__ emb,
                        float* __restrict__ out, int N){
  int i = blockIdx.x*blockDim.x + threadIdx.x;   // N*32 threads
  int n = i >> 5, c = i & 31;
  if(n < N){
    ((float4*)out)[(size_t)n*32 + c] = ((const float4*)emb)[(size_t)idx[n]*32 + c];
  }
}

// ---------------- segment mean (one wave per dst node) ----------------
__global__ void agg_k(const float* __restrict__ x, const int* __restrict__ rp,
                      const int* __restrict__ csr, float* __restrict__ agg, int N){
  int wid = (int)(((size_t)blockIdx.x*blockDim.x + threadIdx.x) >> 6);
  int lane = threadIdx.x & 63;
  if(wid >= N) return;
  int rs = rp[wid], re = rp[wid+1];
  float ax=0.f, ay=0.f;
  for(int j=rs;j<re;j++){
    int s = csr[j];
    float2 v = ((const float2*)x)[(size_t)s*64 + lane];
    ax += v.x; ay += v.y;
  }
  int c = re - rs; if(c < 1) c = 1;
  float inv = 1.0f / (float)c;
  float2 o; o.x = ax*inv; o.y = ay*inv;
  ((float2*)agg)[(size_t)wid*64 + lane] = o;
}

// ---------------- layer GEMM: out = elu(agg@Wl.T + bl + x@Wr.T) ----------------
// 128-row x 128-col tile, 256 threads, 8x8 per thread, K=128 per phase (2 phases)
__global__ __launch_bounds__(256,1) void layer_k(
    const float* __restrict__ agg, const float* __restrict__ x,
    const float* __restrict__ Wl, const float* __restrict__ Wr,
    const float* __restrict__ bl, float* __restrict__ out,
    int N, int transposed){
  __shared__ float WT[128*128];
  __shared__ float AT[128*128];
  int t = threadIdx.x;
  int r0g = blockIdx.x * 128;
  int rg = t & 15, cg = t >> 4;
  int r0 = rg*8, c0 = cg*8;
  float acc[8][8] = {};
  for(int ph=0; ph<2; ph++){
    const float* W = ph ? Wr : Wl;
    const float* A = ph ? x : agg;
    if(ph) __syncthreads();
    #pragma unroll
    for(int i=0;i<16;i++){
      int lin = t + i*256;            // 0..4095
      int c = lin & 127, kg = lin >> 7;
      float4 w = *(const float4*)&W[(size_t)c*H + kg*4];
      WT[(kg*4+0)*128 + c] = w.x;
      WT[(kg*4+1)*128 + c] = w.y;
      WT[(kg*4+2)*128 + c] = w.z;
      WT[(kg*4+3)*128 + c] = w.w;
      float4 a = *(const float4*)&A[(size_t)(r0g + c)*H + kg*4];
      AT[(kg*4+0)*128 + c] = a.x;
      AT[(kg*4+1)*128 + c] = a.y;
      AT[(kg*4+2)*128 + c] = a.z;
      AT[(kg*4+3)*128 + c] = a.w;
    }
    __syncthreads();
    for(int k=0;k<128;k++){
      float4 a0 = *(float4*)&AT[k*128 + r0];
      float4 a1 = *(float4*)&AT[k*128 + r0+4];
      float4 w0 = *(float4*)&WT[k*128 + c0];
      float4 w1 = *(float4*)&WT[k*128 + c0+4];
      float av[8] = {a0.x,a0.y,a0.z,a0.w,a1.x,a1.y,a1.z,a1.w};
      float wv[8] = {w0.x,w0.y,w0.z,w0.w,w1.x,w1.y,w1.z,w1.w};
      #pragma unroll
      for(int rr=0;rr<8;rr++)
        #pragma unroll
        for(int cc=0;cc<8;cc++)
          acc[rr][cc] += av[rr]*wv[cc];
    }
  }
  #pragma unroll
  for(int rr=0;rr<8;rr++)
    #pragma unroll
    for(int cc=0;cc<8;cc++){
      float v = acc[rr][cc] + bl[c0+cc];
      acc[rr][cc] = (v > 0.f) ? v : expm1f(v);
    }
  if(!transposed){
    #pragma unroll
    for(int rr=0;rr<8;rr++){
      float4 v0; v0.x=acc[rr][0]; v0.y=acc[rr][1]; v0.z=acc[rr][2]; v0.w=acc[rr][3];
      float4 v1; v1.x=acc[rr][4]; v1.y=acc[rr][5]; v1.z=acc[rr][6]; v1.w=acc[rr][7];
      size_t off = (size_t)(r0g + r0 + rr)*H + c0;
      *(float4*)&out[off]   = v0;
      *(float4*)&out[off+4] = v1;
    }
  } else {
    #pragma unroll
    for(int cc=0;cc<8;cc++){
      float4 v0; v0.x=acc[0][cc]; v0.y=acc[1][cc]; v0.z=acc[2][cc]; v0.w=acc[3][cc];
      float4 v1; v1.x=acc[4][cc]; v1.y=acc[5][cc]; v1.z=acc[6][cc]; v1.w=acc[7][cc];
      size_t off = (size_t)(c0 + cc)*N + r0g + r0;
      *(float4*)&out[off]   = v0;
      *(float4*)&out[off+4] = v1;
    }
  }
}

// ---------------- attention pass 1: P=exp(masked logits), row partial sums ----------------
__global__ __launch_bounds__(256,1) void att1_k(
    const float* __restrict__ eqT, const float* __restrict__ etT,
    const void* __restrict__ maskp, const int* __restrict__ flag,
    float* __restrict__ out, float* __restrict__ rowsum){
  __shared__ float EQ[128*128];
  __shared__ float ET[128*128];
  __shared__ float red[128*16];
  int t = threadIdx.x;
  int gc0 = blockIdx.x * 128;
  int gr0 = blockIdx.y * 128;
  #pragma unroll
  for(int i=0;i<16;i++){
    int lin4 = t + i*256;               // 0..4095
    int k = lin4 >> 5, c4 = (lin4 & 31)*4;
    *(float4*)&EQ[k*128 + c4] = *(const float4*)&eqT[(size_t)k*N_Q + gr0 + c4];
    *(float4*)&ET[k*128 + c4] = *(const float4*)&etT[(size_t)k*N_T + gc0 + c4];
  }
  __syncthreads();
  int rg = t & 15, cg = t >> 4;
  int r0 = rg*8, c0 = cg*8;
  float acc[8][8] = {};
  for(int k=0;k<128;k++){
    float4 a0 = *(float4*)&EQ[k*128 + r0];
    float4 a1 = *(float4*)&EQ[k*128 + r0+4];
    float4 b0 = *(float4*)&ET[k*128 + c0];
    float4 b1 = *(float4*)&ET[k*128 + c0+4];
    float av[8] = {a0.x,a0.y,a0.z,a0.w,a1.x,a1.y,a1.z,a1.w};
    float bv[8] = {b0.x,b0.y,b0.z,b0.w,b1.x,b1.y,b1.z,b1.w};
    #pragma unroll
    for(int rr=0;rr<8;rr++)
      #pragma unroll
      for(int cc=0;cc<8;cc++)
        acc[rr][cc] += av[rr]*bv[cc];
  }
  const float sc = 0.08838834764831845f;   // 1/sqrt(128)
  int mb = *flag;
  float rsum[8];
  #pragma unroll
  for(int rr=0;rr<8;rr++){
    int row = gr0 + r0 + rr;
    size_t off = (size_t)row * N_T + gc0 + c0;
    float pv[8];
    if(mb & 2){                       // float32 mask
      const float* mp = (const float*)maskp + off;
      float4 m0 = *(const float4*)mp;
      float4 m1 = *(const float4*)(mp+4);
      float mm[8] = {m0.x,m0.y,m0.z,m0.w,m1.x,m1.y,m1.z,m1.w};
      #pragma unroll
      for(int cc=0;cc<8;cc++) pv[cc] = (mm[cc]!=0.f) ? __expf(acc[rr][cc]*sc) : 0.f;
    } else if(mb & 1){                // uint8 bool mask
      const uint8_t* mp = (const uint8_t*)maskp + off;
      uchar4 m0 = *(const uchar4*)mp;
      uchar4 m1 = *(const uchar4*)(mp+4);
      unsigned mm[8] = {m0.x,m0.y,m0.z,m0.w,m1.x,m1.y,m1.z,m1.w};
      #pragma unroll
      for(int cc=0;cc<8;cc++) pv[cc] = mm[cc] ? __expf(acc[rr][cc]*sc) : 0.f;
    } else {                          // int32 mask
      const int* mp = (const int*)maskp + off;
      int4 m0 = *(const int4*)mp;
      int4 m1 = *(const int4*)(mp+4);
      int mm[8] = {m0.x,m0.y,m0.z,m0.w,m1.x,m1.y,m1.z,m1.w};
      #pragma unroll
      for(int cc=0;cc<8;cc++) pv[cc] = mm[cc] ? __expf(acc[rr][cc]*sc) : 0.f;
    }
    float s = 0.f;
    #pragma unroll
    for(int cc=0;cc<8;cc++) s += pv[cc];
    rsum[rr] = s;
    float4 v0; v0.x=pv[0]; v0.y=pv[1]; v0.z=pv[2]; v0.w=pv[3];
    float4 v1; v1.x=pv[4]; v1.y=pv[5]; v1.z=pv[6]; v1.w=pv[7];
    *(float4*)&out[off]   = v0;
    *(float4*)&out[off+4] = v1;
  }
  #pragma unroll
  for(int rr=0;rr<8;rr++) red[(r0+rr)*16 + cg] = rsum[rr];
  __syncthreads();
  if(t < 128){
    float s = 0.f;
    #pragma unroll
    for(int j=0;j<16;j++) s += red[t*16+j];
    atomicAdd(&rowsum[gr0 + t], s);
  }
}

// ---------------- attention pass 2: normalize ----------------
__global__ void att2_k(float* __restrict__ out, const float* __restrict__ rowsum){
  size_t n4 = ((size_t)N_Q * N_T) / 4;
  size_t i = (size_t)blockIdx.x*blockDim.x + threadIdx.x;
  size_t stride = (size_t)gridDim.x*blockDim.x;
  for(; i<n4; i+=stride){
    int r = (int)(i >> 13);          // (i*4)/32768
    float inv = 1.0f / rowsum[r];
    float4 v = ((float4*)out)[i];
    v.x*=inv; v.y*=inv; v.z*=inv; v.w*=inv;
    ((float4*)out)[i] = v;
  }
}

// ---------------- host launch ----------------
extern "C" void kernel_launch(void* const* d_in, const int* in_sizes, int n_in,
                              void* d_out, int out_size, void* d_ws, size_t ws_size,
                              hipStream_t stream){
  const int* tx  = (const int*)d_in[0];
  const int* qx  = (const int*)d_in[1];
  const int* te  = (const int*)d_in[2];
  const int* qe  = (const int*)d_in[3];
  const void* mask = d_in[4];
  const float* emb = (const float*)d_in[5];
  const float* Wl  = (const float*)d_in[6];
  const float* bl  = (const float*)d_in[7];
  const float* Wr  = (const float*)d_in[8];
  float* out = (float*)d_out;
  float* ws  = (float*)d_ws;

  // ws: final transposed features + rowsum + flag (~18.1 MB)
  float* etT    = ws;                                  // 128*32768
  float* eqT    = etT + (size_t)H*N_T;                 // 128*4096
  float* rowsum = eqT + (size_t)H*N_Q;                 // 4096
  int*   flag   = (int*)(rowsum + N_Q);

  // phase-1 scratch lives inside d_out (512MB; overwritten by att1 afterwards)
  float* S    = out;
  float* xt0  = S;
  float* xt1  = S + 4194304;
  float* aggt = S + 8388608;
  float* xq0  = S + 12582912;
  float* xq1  = xq0 + 524288;
  float* aggq = xq1 + 524288;
  int*   ib    = (int*)(aggq + 524288);
  int*   cnt_t = ib;
  int*   rp_t  = cnt_t + N_T;
  int*   pos_t = rp_t + N_T + 1;
  int*   csr_t = pos_t + N_T;
  int*   cnt_q = csr_t + E_T;
  int*   rp_q  = cnt_q + N_Q;
  int*   pos_q = rp_q + N_Q + 1;
  int*   csr_q = pos_q + N_Q;

  zero_i32_k<<<(N_T+255)/256,256,0,stream>>>(cnt_t, N_T);
  zero_i32_k<<<(N_Q+255)/256,256,0,stream>>>(cnt_q, N_Q);
  zero_f32_k<<<(N_Q+255)/256,256,0,stream>>>(rowsum, N_Q);
  zero_i32_k<<<1,256,0,stream>>>(flag, 1);
  detect_mask_k<<<1,256,0,stream>>>((const unsigned*)mask, flag);

  count_k<<<E_T/256,256,0,stream>>>(te+E_T, E_T, cnt_t);
  scan_k<<<1,1024,0,stream>>>(cnt_t, N_T, rp_t, pos_t);
  fill_k<<<E_T/256,256,0,stream>>>(te, te+E_T, E_T, pos_t, csr_t);
  count_k<<<E_Q/256,256,0,stream>>>(qe+E_Q, E_Q, cnt_q);
  scan_k<<<1,1024,0,stream>>>(cnt_q, N_Q, rp_q, pos_q);
  fill_k<<<E_Q/256,256,0,stream>>>(qe, qe+E_Q, E_Q, pos_q, csr_q);

  embed_k<<<N_T*32/256,256,0,stream>>>(tx, emb, xt0, N_T);
  embed_k<<<N_Q*32/256,256,0,stream>>>(qx, emb, xq0, N_Q);

  float* ct = xt0; float* nt = xt1;
  float* cq = xq0; float* nq = xq1;
  for(int l=0;l<NL;l++){
    int last = (l == NL-1);
    agg_k<<<N_T/4,256,0,stream>>>(ct, rp_t, csr_t, aggt, N_T);
    layer_k<<<N_T/128,256,0,stream>>>(aggt, ct, Wl+(size_t)l*H*H, Wr+(size_t)l*H*H,
                                      bl+(size_t)l*H, last ? etT : nt, N_T, last);
    agg_k<<<N_Q/4,256,0,stream>>>(cq, rp_q, csr_q, aggq, N_Q);
    layer_k<<<N_Q/128,256,0,stream>>>(aggq, cq, Wl+(size_t)l*H*H, Wr+(size_t)l*H*H,
                                      bl+(size_t)l*H, last ? eqT : nq, N_Q, last);
    float* tmp;
    tmp = ct; ct = nt; nt = tmp;
    tmp = cq; cq = nq; nq = tmp;
  }

  att1_k<<<dim3(N_T/128, N_Q/128),256,0,stream>>>(eqT, etT, mask, flag, out, rowsum);
  att2_k<<<8192,256,0,stream>>>(out, rowsum);
}